// Round 5
// baseline (227209.644 us; speedup 1.0000x reference)
//
#include <hip/hip_runtime.h>

#define B_ 16
#define ENC_D_ 512
#define ENC_T_ 256
#define FEAT_D_ 513
#define DEC_T_ 512
#define ATT_ 128
#define NWG_ 256

typedef unsigned short u16;

__device__ __forceinline__ float b2f(u16 x) {
  unsigned u = ((unsigned)x) << 16;
  return __builtin_bit_cast(float, u);
}
__device__ __forceinline__ float ldin(const void* p, long i, bool f32) {
  return f32 ? ((const float*)p)[i] : b2f(((const u16*)p)[i]);
}
__device__ __forceinline__ float sigm_p(float x) {
  return 1.f / (1.f + expf(-x));
}

__device__ __forceinline__ void gbar(unsigned* cnt, unsigned* gen, unsigned& mygen) {
  __threadfence();
  __syncthreads();
  ++mygen;
  if (threadIdx.x == 0) {
    if (__hip_atomic_fetch_add(cnt, 1u, __ATOMIC_ACQ_REL, __HIP_MEMORY_SCOPE_AGENT) == NWG_ - 1u) {
      __hip_atomic_store(cnt, 0u, __ATOMIC_RELAXED, __HIP_MEMORY_SCOPE_AGENT);
      __hip_atomic_store(gen, mygen, __ATOMIC_RELEASE, __HIP_MEMORY_SCOPE_AGENT);
    } else {
      while (__hip_atomic_load(gen, __ATOMIC_RELAXED, __HIP_MEMORY_SCOPE_AGENT) < mygen)
        __builtin_amdgcn_s_sleep(1);
    }
  }
  __syncthreads();
  __threadfence();
}

// float dtype detect: 0 = bf16 inputs, 1 = fp32 inputs (sample prenet_w0 even u16s)
__global__ void k_detect(const u16* __restrict__ w, int* flag) {
  __shared__ int cnt;
  if (threadIdx.x == 0) cnt = 0;
  __syncthreads();
  int c = 0;
  for (int i = threadIdx.x; i < 512; i += 256) {
    u16 v = w[2 * i];
    int e = (v >> 7) & 0xFF;
    if (e >= 80 && e <= 140) c++;
  }
  atomicAdd(&cnt, c);
  __syncthreads();
  if (threadIdx.x == 0) *flag = (cnt >= 384) ? 0 : 1;
}

// encoding_lengths format detect (int32 fires first and is correct; kept for safety)
__global__ void k_lens(const void* __restrict__ raw, int* __restrict__ lens_out) {
  if (threadIdx.x != 0 || blockIdx.x != 0) return;
  const int* i32 = (const int*)raw;
  const long long* i64 = (const long long*)raw;
  const float* f32 = (const float*)raw;
  const double* f64 = (const double*)raw;
  bool ok;
  ok = true;
  for (int b = 0; b < B_; ++b) { int v = i32[b]; if (v < 1 || v > ENC_T_) ok = false; }
  if (ok) { for (int b = 0; b < B_; ++b) lens_out[b] = i32[b]; return; }
  ok = true;
  for (int b = 0; b < B_; ++b) { long long v = i64[b]; if (v < 1 || v > ENC_T_) ok = false; }
  if (ok) { for (int b = 0; b < B_; ++b) lens_out[b] = (int)i64[b]; return; }
  ok = true;
  for (int b = 0; b < B_; ++b) { float x = f32[b]; if (!(x >= 1.f && x <= 256.f && x == floorf(x))) ok = false; }
  if (ok) { for (int b = 0; b < B_; ++b) lens_out[b] = (int)f32[b]; return; }
  ok = true;
  for (int b = 0; b < B_; ++b) { double x = f64[b]; if (!(x >= 1.0 && x <= 256.0 && x == floor(x))) ok = false; }
  if (ok) { for (int b = 0; b < B_; ++b) lens_out[b] = (int)f64[b]; return; }
  for (int b = 0; b < B_; ++b) {
    int v = i32[b];
    lens_out[b] = v < 1 ? 1 : (v > ENC_T_ ? ENC_T_ : v);
  }
}

// convert one tensor to fp32 in ws
__global__ void k_cvt32(const void* __restrict__ src, float* __restrict__ dst, int n,
                        const int* __restrict__ flag) {
  bool f32 = (*flag) != 0;
  int stride = blockDim.x * gridDim.x;
  for (int i = threadIdx.x + blockIdx.x * blockDim.x; i < n; i += stride)
    dst[i] = f32 ? ((const float*)src)[i] : b2f(((const u16*)src)[i]);
}

__global__ void k_init2(float* h1f, float* h2f, float* ctxf, float* c1f, float* c2f,
                        float* alignf, float* cumf, unsigned* bar_cnt, unsigned* bar_gen) {
  int tid = threadIdx.x + blockIdx.x * blockDim.x;
  int stride = blockDim.x * gridDim.x;
  for (int i = tid; i < 2 * B_ * 1024; i += stride) { h1f[i] = 0.f; h2f[i] = 0.f; }
  for (int i = tid; i < B_ * 512; i += stride) ctxf[i] = 0.f;
  for (int i = tid; i < B_ * 1024; i += stride) { c1f[i] = 0.f; c2f[i] = 0.f; }
  for (int i = tid; i < B_ * ENC_T_; i += stride) {
    float v = ((i & (ENC_T_ - 1)) == 0) ? 1.f : 0.f;
    alignf[i] = v; cumf[i] = v;
  }
  if (tid == 0) { *bar_cnt = 0u; *bar_gen = 0u; }
}

// prenet for all timesteps, fp32 out
__global__ __launch_bounds__(256) void k_prenet32(const void* __restrict__ feats,
                                                  const void* __restrict__ go,
                                                  const void* __restrict__ w0,
                                                  const void* __restrict__ w1,
                                                  float* __restrict__ pre,
                                                  const int* __restrict__ flag) {
  const bool f32 = (*flag) != 0;
  int t = blockIdx.x, tid = threadIdx.x;
  __shared__ __align__(16) float din[FEAT_D_][16];
  __shared__ __align__(16) float o1[256][16];
  for (int idx = tid; idx < 16 * FEAT_D_; idx += 256) {
    int f = idx >> 4, b = idx & 15;
    float v = (t == 0) ? ldin(go, f, f32)
                       : ldin(feats, ((long)b * FEAT_D_ + f) * DEC_T_ + (t - 1), f32);
    din[f][b] = v;
  }
  __syncthreads();
  float acc[16];
#pragma unroll
  for (int b = 0; b < 16; ++b) acc[b] = 0.f;
  for (int f = 0; f < FEAT_D_; ++f) {
    float w = ldin(w0, (long)tid * FEAT_D_ + f, f32);
#pragma unroll
    for (int b = 0; b < 16; ++b) acc[b] += w * din[f][b];
  }
#pragma unroll
  for (int b = 0; b < 16; ++b) o1[tid][b] = fmaxf(acc[b], 0.f);
  __syncthreads();
#pragma unroll
  for (int b = 0; b < 16; ++b) acc[b] = 0.f;
  for (int r1 = 0; r1 < 256; ++r1) {
    float w = ldin(w1, (long)tid * 256 + r1, f32);
#pragma unroll
    for (int b = 0; b < 16; ++b) acc[b] += w * o1[r1][b];
  }
#pragma unroll
  for (int b = 0; b < 16; ++b)
    pre[((long)t * 16 + b) * 256 + tid] = fmaxf(acc[b], 0.f);
}

// encoder transpose (fp32) + processed-memory
__global__ __launch_bounds__(256) void k_mem32(const void* __restrict__ enc,
                                               const void* __restrict__ wmem,
                                               float* __restrict__ mem_t,
                                               float* __restrict__ pm,
                                               const int* __restrict__ flag) {
  const bool f32 = (*flag) != 0;
  int b = blockIdx.x >> 4, tc = blockIdx.x & 15;
  int t0 = tc * 16, tid = threadIdx.x;
  __shared__ __align__(16) float et[16][ENC_D_];
  for (int idx = tid; idx < ENC_D_ * 16; idx += 256) {
    int d = idx >> 4, i = idx & 15;
    et[i][d] = ldin(enc, ((long)b * ENC_D_ + d) * ENC_T_ + t0 + i, f32);
  }
  __syncthreads();
  for (int idx = tid; idx < 16 * ENC_D_; idx += 256) {
    int i = idx >> 9, d = idx & 511;
    mem_t[((long)b * ENC_T_ + t0 + i) * ENC_D_ + d] = et[i][d];
  }
  int a = tid & 127;
#pragma unroll 1
  for (int jj = 0; jj < 8; ++jj) {
    int i = ((tid >> 7) << 3) + jj;
    float s = 0.f;
    for (int d = 0; d < ENC_D_; ++d)
      s += ldin(wmem, (long)a * ENC_D_ + d, f32) * et[i][d];
    pm[((long)b * ATT_ + a) * ENC_T_ + t0 + i] = s;
  }
}

// ---------------- persistent decoder: all-fp32 VALU, fp32 outputs ----------------
__global__ __launch_bounds__(256) void k_main_v(
    const float* __restrict__ wih1, const float* __restrict__ whh1, const float* __restrict__ b1,
    const float* __restrict__ wih2, const float* __restrict__ whh2, const float* __restrict__ b2,
    const float* __restrict__ wq, const float* __restrict__ wconv, const float* __restrict__ wdense,
    const float* __restrict__ vv, const float* __restrict__ wproj, const float* __restrict__ bproj,
    const int* __restrict__ lens,
    const float* __restrict__ pre, const float* __restrict__ mem_t, const float* __restrict__ pm,
    float* s_tmp, float* h1f, float* h2f, float* ctxf, float* c1f, float* c2f,
    float* alignf, float* cumf, unsigned* bar_cnt, unsigned* bar_gen,
    float* outf, float* outa) {
  const int wg = blockIdx.x, tid = threadIdx.x;
  const int wid = tid >> 6, lane = tid & 63;
  const int rr = tid >> 4, bi = tid & 15;
  const int g = rr >> 2, du = rr & 3;
  const int u0 = wg << 2;
  const int wrow = (g << 10) + u0 + du;  // gate-major weight row

  __shared__ float gsh[16][17];
  __shared__ float loc_in[2][64];
  __shared__ float loc_f_s[32][16];
  __shared__ float att_s[2][128];
  __shared__ float v_s[128];
  __shared__ float align_s[256];
  __shared__ float sred[8];

  unsigned mygen = 0;
  const int sb = wg >> 4;          // batch for s_tmp slice
  const int st0 = (wg & 15) << 4;  // t' base for s_tmp slice

#pragma unroll 1
  for (int t = 0; t < DEC_T_; ++t) {
    const int cb = t & 1, pb = cb ^ 1;
    // ========== PHASE A ==========
    // (a) location features: s_tmp[b][a][t'] = pm + dense(conv(align,cum))
    {
      if (tid < 128) {
        int i = tid & 63, ch = tid >> 6;
        int tg = st0 - 16 + i;
        float val = 0.f;
        if (tg >= 0 && tg < ENC_T_) val = (ch == 0 ? alignf : cumf)[sb * ENC_T_ + tg];
        loc_in[ch][i] = val;
      }
      __syncthreads();
#pragma unroll
      for (int rep = 0; rep < 2; ++rep) {
        int o = tid + rep * 256;
        int c = o >> 4, j = o & 15;
        float s = 0.f;
#pragma unroll
        for (int k = 0; k < 31; ++k) {
          s += loc_in[0][j + 1 + k] * wconv[c * 62 + k];
          s += loc_in[1][j + 1 + k] * wconv[c * 62 + 31 + k];
        }
        loc_f_s[c][j] = s;
      }
      __syncthreads();
      {
        int a = tid & 127;
#pragma unroll 1
        for (int jj = 0; jj < 8; ++jj) {
          int j = ((tid >> 7) << 3) + jj;
          long idx = ((long)sb * ATT_ + a) * ENC_T_ + st0 + j;
          float s = pm[idx];
#pragma unroll
          for (int c = 0; c < 32; ++c) s += loc_f_s[c][j] * wdense[a * 32 + c];
          s_tmp[idx] = s;
        }
      }
    }
    // (b) gates1 = Wih1 @ [pre_t | ctx_{t-1}] + Whh1 @ h1_{t-1} + b1
    {
      const float* wr = wih1 + (long)wrow * 768;
      const float* whr = whh1 + (long)wrow * 1024;
      const float* xp = pre + ((long)t * 16 + bi) * 256;
      const float* cp = ctxf + bi * 512;
      const float* hp = h1f + pb * (B_ * 1024) + bi * 1024;
      float a0 = 0, a1 = 0, a2 = 0, a3 = 0;
      for (int k = 0; k < 256; k += 4) {
        float4 w = *(const float4*)(wr + k); float4 x = *(const float4*)(xp + k);
        a0 += w.x * x.x; a1 += w.y * x.y; a2 += w.z * x.z; a3 += w.w * x.w;
      }
      for (int k = 0; k < 512; k += 4) {
        float4 w = *(const float4*)(wr + 256 + k); float4 x = *(const float4*)(cp + k);
        a0 += w.x * x.x; a1 += w.y * x.y; a2 += w.z * x.z; a3 += w.w * x.w;
      }
      for (int k = 0; k < 1024; k += 4) {
        float4 w = *(const float4*)(whr + k); float4 x = *(const float4*)(hp + k);
        a0 += w.x * x.x; a1 += w.y * x.y; a2 += w.z * x.z; a3 += w.w * x.w;
      }
      gsh[rr][bi] = a0 + a1 + a2 + a3 + b1[wrow];
    }
    __syncthreads();
    if (tid < 64) {
      int du2 = tid >> 4, bi2 = tid & 15, unit = u0 + du2;
      float gi = gsh[du2][bi2], gf = gsh[4 + du2][bi2];
      float gg = gsh[8 + du2][bi2], go = gsh[12 + du2][bi2];
      float cold = c1f[bi2 * 1024 + unit];
      float cn = sigm_p(gf) * cold + sigm_p(gi) * tanhf(gg);
      c1f[bi2 * 1024 + unit] = cn;
      h1f[cb * (B_ * 1024) + bi2 * 1024 + unit] = sigm_p(go) * tanhf(cn);
    }
    gbar(bar_cnt, bar_gen, mygen);
    // ========== PHASE B: attention (one WG per batch) ==========
    if (wg < B_) {
      const int ab = wg;
      const int len_b = lens[ab];
      {
        int a = tid & 127, h = tid >> 7;
        const float* wr = wq + (long)a * 1024 + h * 512;
        const float* hr = h1f + cb * (B_ * 1024) + ab * 1024 + h * 512;
        float p0 = 0, p1 = 0, p2 = 0, p3 = 0;
        for (int k = 0; k < 512; k += 4) {
          float4 w = *(const float4*)(wr + k); float4 x = *(const float4*)(hr + k);
          p0 += w.x * x.x; p1 += w.y * x.y; p2 += w.z * x.z; p3 += w.w * x.w;
        }
        att_s[h][a] = p0 + p1 + p2 + p3;
      }
      if (tid < 128) v_s[tid] = vv[tid];
      __syncthreads();
      if (tid < 128) att_s[0][tid] += att_s[1][tid];
      __syncthreads();
      float e;
      {
        const float* sc = s_tmp + ((long)ab * ATT_) * ENC_T_ + tid;
        float acc = 0.f;
#pragma unroll 4
        for (int a = 0; a < 128; ++a)
          acc += tanhf(sc[(long)a * ENC_T_] + att_s[0][a]) * v_s[a];
        e = (tid >= len_b) ? -1e9f : acc;
      }
      float mx = e;
#pragma unroll
      for (int off = 32; off; off >>= 1) mx = fmaxf(mx, __shfl_xor(mx, off));
      if (lane == 0) sred[wid] = mx;
      __syncthreads();
      mx = fmaxf(fmaxf(sred[0], sred[1]), fmaxf(sred[2], sred[3]));
      float ex = expf(e - mx);
      float sm = ex;
#pragma unroll
      for (int off = 32; off; off >>= 1) sm += __shfl_xor(sm, off);
      if (lane == 0) sred[4 + wid] = sm;
      __syncthreads();
      sm = sred[4] + sred[5] + sred[6] + sred[7];
      float al = ex / sm;
      align_s[tid] = al;
      alignf[ab * ENC_T_ + tid] = al;
      cumf[ab * ENC_T_ + tid] += al;
      outa[((long)ab * ENC_T_ + tid) * DEC_T_ + t] = al;
      __syncthreads();
      {
        const float* mt = mem_t + (long)ab * ENC_T_ * ENC_D_;
        float c0 = 0.f, c1v = 0.f;
#pragma unroll 2
        for (int tp = 0; tp < ENC_T_; ++tp) {
          float av = align_s[tp];
          c0 += av * mt[(long)tp * ENC_D_ + tid];
          c1v += av * mt[(long)tp * ENC_D_ + tid + 256];
        }
        ctxf[ab * 512 + tid] = c0;
        ctxf[ab * 512 + tid + 256] = c1v;
      }
    }
    gbar(bar_cnt, bar_gen, mygen);
    // ========== PHASE C: gates2 = Wih2 @ [h1_t | ctx_t] + Whh2 @ h2_{t-1} + b2 ====
    {
      const float* wr = wih2 + (long)wrow * 1536;
      const float* whr = whh2 + (long)wrow * 1024;
      const float* hp1 = h1f + cb * (B_ * 1024) + bi * 1024;
      const float* cp = ctxf + bi * 512;
      const float* hp2 = h2f + pb * (B_ * 1024) + bi * 1024;
      float a0 = 0, a1 = 0, a2 = 0, a3 = 0;
      for (int k = 0; k < 1024; k += 4) {
        float4 w = *(const float4*)(wr + k); float4 x = *(const float4*)(hp1 + k);
        a0 += w.x * x.x; a1 += w.y * x.y; a2 += w.z * x.z; a3 += w.w * x.w;
      }
      for (int k = 0; k < 512; k += 4) {
        float4 w = *(const float4*)(wr + 1024 + k); float4 x = *(const float4*)(cp + k);
        a0 += w.x * x.x; a1 += w.y * x.y; a2 += w.z * x.z; a3 += w.w * x.w;
      }
      for (int k = 0; k < 1024; k += 4) {
        float4 w = *(const float4*)(whr + k); float4 x = *(const float4*)(hp2 + k);
        a0 += w.x * x.x; a1 += w.y * x.y; a2 += w.z * x.z; a3 += w.w * x.w;
      }
      gsh[rr][bi] = a0 + a1 + a2 + a3 + b2[wrow];
    }
    __syncthreads();
    if (tid < 64) {
      int du2 = tid >> 4, bi2 = tid & 15, unit = u0 + du2;
      float gi = gsh[du2][bi2], gf = gsh[4 + du2][bi2];
      float gg = gsh[8 + du2][bi2], go = gsh[12 + du2][bi2];
      float cold = c2f[bi2 * 1024 + unit];
      float cn = sigm_p(gf) * cold + sigm_p(gi) * tanhf(gg);
      c2f[bi2 * 1024 + unit] = cn;
      h2f[cb * (B_ * 1024) + bi2 * 1024 + unit] = sigm_p(go) * tanhf(cn);
    }
    gbar(bar_cnt, bar_gen, mygen);
    // ========== PHASE D: proj_t = [h2_t | ctx_t] @ projW^T + b ==========
    if (wg < 33) {
      int row = wg * 16 + rr;
      if (row < FEAT_D_) {
        const float* wr = wproj + (long)row * 1536;
        const float* hp2 = h2f + cb * (B_ * 1024) + bi * 1024;
        const float* cp = ctxf + bi * 512;
        float a0 = 0, a1 = 0, a2 = 0, a3 = 0;
        for (int k = 0; k < 1024; k += 4) {
          float4 w = *(const float4*)(wr + k); float4 x = *(const float4*)(hp2 + k);
          a0 += w.x * x.x; a1 += w.y * x.y; a2 += w.z * x.z; a3 += w.w * x.w;
        }
        for (int k = 0; k < 512; k += 4) {
          float4 w = *(const float4*)(wr + 1024 + k); float4 x = *(const float4*)(cp + k);
          a0 += w.x * x.x; a1 += w.y * x.y; a2 += w.z * x.z; a3 += w.w * x.w;
        }
        float s = a0 + a1 + a2 + a3 + bproj[row];
        outf[((long)bi * FEAT_D_ + row) * DEC_T_ + t] = s;
      }
    }
    // no barrier needed before next phase A (no read/write overlap across it)
  }
}

extern "C" void kernel_launch(void* const* d_in, const int* in_sizes, int n_in,
                              void* d_out, int out_size, void* d_ws, size_t ws_size,
                              hipStream_t stream) {
  const void* enc   = d_in[0];
  const void* feats = d_in[2];
  const void* go    = d_in[3];
  const void* w0    = d_in[4];
  const void* w1    = d_in[5];

  float* outf = (float*)d_out;                         // [16][513][512] fp32
  float* outa = outf + (size_t)B_ * FEAT_D_ * DEC_T_;  // [16][256][512] fp32

  char* ws = (char*)d_ws;
  size_t off = 0;
  auto take = [&](size_t bytes) { char* p = ws + off; off += (bytes + 255) & ~size_t(255); return p; };
  int*   flag   = (int*)take(256);
  int*   lens_d = (int*)take(256);
  float* pre    = (float*)take((size_t)DEC_T_ * B_ * 256 * 4);
  float* mem_t  = (float*)take((size_t)B_ * ENC_T_ * ENC_D_ * 4);
  float* pm     = (float*)take((size_t)B_ * ATT_ * ENC_T_ * 4);
  float* s_tmp  = (float*)take((size_t)B_ * ATT_ * ENC_T_ * 4);
  float* h1f    = (float*)take((size_t)2 * B_ * 1024 * 4);
  float* h2f    = (float*)take((size_t)2 * B_ * 1024 * 4);
  float* ctxf   = (float*)take((size_t)B_ * 512 * 4);
  float* c1f    = (float*)take((size_t)B_ * 1024 * 4);
  float* c2f    = (float*)take((size_t)B_ * 1024 * 4);
  float* alignf = (float*)take((size_t)B_ * ENC_T_ * 4);
  float* cumf   = (float*)take((size_t)B_ * ENC_T_ * 4);
  unsigned* bar_cnt = (unsigned*)take(256);
  unsigned* bar_gen = (unsigned*)take(256);
  // fp32 copies of decoder weights:
  float* wih1   = (float*)take((size_t)4096 * 768 * 4);
  float* whh1   = (float*)take((size_t)4096 * 1024 * 4);
  float* b1c    = (float*)take((size_t)4096 * 4);
  float* wih2   = (float*)take((size_t)4096 * 1536 * 4);
  float* whh2   = (float*)take((size_t)4096 * 1024 * 4);
  float* b2c    = (float*)take((size_t)4096 * 4);
  float* wqc    = (float*)take((size_t)128 * 1024 * 4);
  float* wconvc = (float*)take((size_t)32 * 2 * 31 * 4);
  float* wdensec= (float*)take((size_t)128 * 32 * 4);
  float* vvc    = (float*)take((size_t)128 * 4);
  float* wprojc = (float*)take((size_t)513 * 1536 * 4);
  float* bprojc = (float*)take((size_t)513 * 4);

  k_detect<<<1, 256, 0, stream>>>((const u16*)d_in[4], flag);
  k_lens<<<1, 64, 0, stream>>>(d_in[1], lens_d);

  struct CvtJob { const void* src; float* dst; int n; };
  const CvtJob jobs[12] = {
      {d_in[6],  wih1,   4096 * 768},
      {d_in[7],  whh1,   4096 * 1024},
      {d_in[8],  b1c,    4096},
      {d_in[9],  wih2,   4096 * 1536},
      {d_in[10], whh2,   4096 * 1024},
      {d_in[11], b2c,    4096},
      {d_in[12], wqc,    128 * 1024},
      {d_in[14], wconvc, 32 * 2 * 31},
      {d_in[15], wdensec, 128 * 32},
      {d_in[16], vvc,    128},
      {d_in[17], wprojc, 513 * 1536},
      {d_in[18], bprojc, 513},
  };
  for (int i = 0; i < 12; ++i) {
    int blocks = (jobs[i].n + 255) / 256;
    if (blocks > 512) blocks = 512;
    k_cvt32<<<blocks, 256, 0, stream>>>(jobs[i].src, jobs[i].dst, jobs[i].n, flag);
  }

  k_init2<<<32, 256, 0, stream>>>(h1f, h2f, ctxf, c1f, c2f, alignf, cumf, bar_cnt, bar_gen);
  k_prenet32<<<DEC_T_, 256, 0, stream>>>(feats, go, w0, w1, pre, flag);
  k_mem32<<<256, 256, 0, stream>>>(enc, d_in[13], mem_t, pm, flag);
  k_main_v<<<NWG_, 256, 0, stream>>>(wih1, whh1, b1c, wih2, whh2, b2c, wqc, wconvc, wdensec,
                                     vvc, wprojc, bprojc, lens_d, pre, mem_t, pm, s_tmp,
                                     h1f, h2f, ctxf, c1f, c2f, alignf, cumf,
                                     bar_cnt, bar_gen, outf, outa);
}

// Round 6
// 106531.396 us; speedup vs baseline: 2.1328x; 2.1328x over previous
//
#include <hip/hip_runtime.h>

#define B_ 16
#define ENC_D_ 512
#define ENC_T_ 256
#define FEAT_D_ 513
#define DEC_T_ 512
#define ATT_ 128
#define NWG_ 256

typedef unsigned short u16;
typedef __attribute__((ext_vector_type(8))) short bf16x8;
typedef __attribute__((ext_vector_type(4))) float f32x4;

__device__ __forceinline__ float b2f(u16 x) {
  unsigned u = ((unsigned)x) << 16;
  return __builtin_bit_cast(float, u);
}
__device__ __forceinline__ u16 f2b(float f) {
  unsigned u = __builtin_bit_cast(unsigned, f);
  u += 0x7FFFu + ((u >> 16) & 1u);
  return (u16)(u >> 16);
}
__device__ __forceinline__ float ldin(const void* p, long i, bool f32) {
  return f32 ? ((const float*)p)[i] : b2f(((const u16*)p)[i]);
}
__device__ __forceinline__ float sigm(float x) {
  return __builtin_amdgcn_rcpf(1.f + __expf(-x));
}
__device__ __forceinline__ float tanh_fast(float x) {
  float e = __expf(2.f * x);
  return 1.f - 2.f * __builtin_amdgcn_rcpf(e + 1.f);
}

__device__ __forceinline__ void gbar(unsigned* cnt, unsigned* gen, unsigned& mygen) {
  __threadfence();
  __syncthreads();
  ++mygen;
  if (threadIdx.x == 0) {
    if (__hip_atomic_fetch_add(cnt, 1u, __ATOMIC_ACQ_REL, __HIP_MEMORY_SCOPE_AGENT) == NWG_ - 1u) {
      __hip_atomic_store(cnt, 0u, __ATOMIC_RELAXED, __HIP_MEMORY_SCOPE_AGENT);
      __hip_atomic_store(gen, mygen, __ATOMIC_RELEASE, __HIP_MEMORY_SCOPE_AGENT);
    } else {
      while (__hip_atomic_load(gen, __ATOMIC_RELAXED, __HIP_MEMORY_SCOPE_AGENT) < mygen)
        __builtin_amdgcn_s_sleep(1);
    }
  }
  __syncthreads();
  __threadfence();
}

// float dtype detect: 0 = bf16 inputs, 1 = fp32 inputs (sample prenet_w0 even u16s)
__global__ void k_detect(const u16* __restrict__ w, int* flag) {
  __shared__ int cnt;
  if (threadIdx.x == 0) cnt = 0;
  __syncthreads();
  int c = 0;
  for (int i = threadIdx.x; i < 512; i += 256) {
    u16 v = w[2 * i];
    int e = (v >> 7) & 0xFF;
    if (e >= 80 && e <= 140) c++;
  }
  atomicAdd(&cnt, c);
  __syncthreads();
  if (threadIdx.x == 0) *flag = (cnt >= 384) ? 0 : 1;
}

// encoding_lengths format detect (int32 is the real format; kept for safety)
__global__ void k_lens(const void* __restrict__ raw, int* __restrict__ lens_out) {
  if (threadIdx.x != 0 || blockIdx.x != 0) return;
  const int* i32 = (const int*)raw;
  const long long* i64 = (const long long*)raw;
  const float* f32 = (const float*)raw;
  const double* f64 = (const double*)raw;
  bool ok;
  ok = true;
  for (int b = 0; b < B_; ++b) { int v = i32[b]; if (v < 1 || v > ENC_T_) ok = false; }
  if (ok) { for (int b = 0; b < B_; ++b) lens_out[b] = i32[b]; return; }
  ok = true;
  for (int b = 0; b < B_; ++b) { long long v = i64[b]; if (v < 1 || v > ENC_T_) ok = false; }
  if (ok) { for (int b = 0; b < B_; ++b) lens_out[b] = (int)i64[b]; return; }
  ok = true;
  for (int b = 0; b < B_; ++b) { float x = f32[b]; if (!(x >= 1.f && x <= 256.f && x == floorf(x))) ok = false; }
  if (ok) { for (int b = 0; b < B_; ++b) lens_out[b] = (int)f32[b]; return; }
  ok = true;
  for (int b = 0; b < B_; ++b) { double x = f64[b]; if (!(x >= 1.0 && x <= 256.0 && x == floor(x))) ok = false; }
  if (ok) { for (int b = 0; b < B_; ++b) lens_out[b] = (int)f64[b]; return; }
  for (int b = 0; b < B_; ++b) {
    int v = i32[b];
    lens_out[b] = v < 1 ? 1 : (v > ENC_T_ ? ENC_T_ : v);
  }
}

// convert one tensor to bf16 in ws (from fp32 or bf16 source)
__global__ void k_cvt(const void* __restrict__ src, u16* __restrict__ dst, int n,
                      const int* __restrict__ flag) {
  bool f32 = (*flag) != 0;
  int stride = blockDim.x * gridDim.x;
  for (int i = threadIdx.x + blockIdx.x * blockDim.x; i < n; i += stride)
    dst[i] = f32 ? f2b(((const float*)src)[i]) : ((const u16*)src)[i];
}

// init: zero states, set align0/cum0, barrier vars
__global__ void k_init(u16* h1g, u16* h2g, u16* ctxg, float* c1g, float* c2g,
                       float* alignf, float* cumf, unsigned* bar_cnt, unsigned* bar_gen) {
  int tid = threadIdx.x + blockIdx.x * blockDim.x;
  int stride = blockDim.x * gridDim.x;
  for (int i = tid; i < 2 * B_ * 1024; i += stride) h1g[i] = 0;
  for (int i = tid; i < B_ * 1024; i += stride) h2g[i] = 0;
  for (int i = tid; i < 2 * B_ * 512; i += stride) ctxg[i] = 0;
  for (int i = tid; i < B_ * 1024; i += stride) { c1g[i] = 0.f; c2g[i] = 0.f; }
  for (int i = tid; i < B_ * ENC_T_; i += stride) {
    float v = ((i & (ENC_T_ - 1)) == 0) ? 1.f : 0.f;
    alignf[i] = v; cumf[i] = v;
  }
  if (tid == 0) { *bar_cnt = 0u; *bar_gen = 0u; }
}

// prenet for all timesteps (teacher-forced, recurrence-free), bf16 out
__global__ __launch_bounds__(256) void k_prenet(const void* __restrict__ feats,
                                                const void* __restrict__ go,
                                                const void* __restrict__ w0,
                                                const void* __restrict__ w1,
                                                u16* __restrict__ pre,
                                                const int* __restrict__ flag) {
  const bool f32 = (*flag) != 0;
  int t = blockIdx.x, tid = threadIdx.x;
  __shared__ __align__(16) float din[FEAT_D_][16];
  __shared__ __align__(16) float o1[256][16];
  for (int idx = tid; idx < 16 * FEAT_D_; idx += 256) {
    int f = idx >> 4, b = idx & 15;
    float v = (t == 0) ? ldin(go, f, f32)
                       : ldin(feats, ((long)b * FEAT_D_ + f) * DEC_T_ + (t - 1), f32);
    din[f][b] = v;
  }
  __syncthreads();
  float acc[16];
#pragma unroll
  for (int b = 0; b < 16; ++b) acc[b] = 0.f;
  for (int f = 0; f < FEAT_D_; ++f) {
    float w = ldin(w0, (long)tid * FEAT_D_ + f, f32);
#pragma unroll
    for (int b = 0; b < 16; ++b) acc[b] += w * din[f][b];
  }
#pragma unroll
  for (int b = 0; b < 16; ++b) o1[tid][b] = fmaxf(acc[b], 0.f);
  __syncthreads();
#pragma unroll
  for (int b = 0; b < 16; ++b) acc[b] = 0.f;
  for (int r1 = 0; r1 < 256; ++r1) {
    float w = ldin(w1, (long)tid * 256 + r1, f32);
#pragma unroll
    for (int b = 0; b < 16; ++b) acc[b] += w * o1[r1][b];
  }
#pragma unroll
  for (int b = 0; b < 16; ++b)
    pre[((long)t * 16 + b) * 256 + tid] = f2b(fmaxf(acc[b], 0.f));
}

// encoder transpose (bf16) + processed-memory (fp32)
__global__ __launch_bounds__(256) void k_mem(const void* __restrict__ enc,
                                             const void* __restrict__ wmem,
                                             u16* __restrict__ mem_t,
                                             float* __restrict__ pm,
                                             const int* __restrict__ flag) {
  const bool f32 = (*flag) != 0;
  int b = blockIdx.x >> 4, tc = blockIdx.x & 15;
  int t0 = tc * 16, tid = threadIdx.x;
  __shared__ __align__(16) float et[16][ENC_D_];
  for (int idx = tid; idx < ENC_D_ * 16; idx += 256) {
    int d = idx >> 4, i = idx & 15;
    et[i][d] = ldin(enc, ((long)b * ENC_D_ + d) * ENC_T_ + t0 + i, f32);
  }
  __syncthreads();
  for (int idx = tid; idx < 16 * ENC_D_; idx += 256) {
    int i = idx >> 9, d = idx & 511;
    mem_t[((long)b * ENC_T_ + t0 + i) * ENC_D_ + d] = f2b(et[i][d]);
  }
  int a = tid & 127;
#pragma unroll 1
  for (int jj = 0; jj < 8; ++jj) {
    int i = ((tid >> 7) << 3) + jj;
    float s = 0.f;
    for (int d = 0; d < ENC_D_; ++d)
      s += ldin(wmem, (long)a * ENC_D_ + d, f32) * et[i][d];
    pm[((long)b * ATT_ + a) * ENC_T_ + t0 + i] = s;
  }
}

// ---------------- persistent decoder: bf16 MFMA, fp32 outputs ----------------
__global__ __launch_bounds__(256) void k_main(
    const u16* __restrict__ wih1, const u16* __restrict__ whh1, const u16* __restrict__ b1,
    const u16* __restrict__ wih2, const u16* __restrict__ whh2, const u16* __restrict__ b2,
    const u16* __restrict__ wq, const u16* __restrict__ wconv, const u16* __restrict__ wdense,
    const u16* __restrict__ vv, const u16* __restrict__ wproj, const u16* __restrict__ bproj,
    const int* __restrict__ lens,
    const u16* __restrict__ pre, const u16* __restrict__ mem_t, const float* __restrict__ pm,
    float* s_tmp, u16* h1g, u16* h2g, u16* ctxg, float* c1g, float* c2g,
    float* alignf, float* cumf, unsigned* bar_cnt, unsigned* bar_gen,
    float* outf, float* outa) {
  const int wg = blockIdx.x, tid = threadIdx.x;
  const int wid = tid >> 6, lane = tid & 63;
  const int m = lane & 15, q = lane >> 4;
  const int u0 = wg << 2;
  const int grow = ((m >> 2) << 10) + u0 + (m & 3);  // mixed i/f/g/o row for this lane
  const int bb = m;                                  // B-frag batch index

  __shared__ __align__(16) float red[4][64][4];
  __shared__ float loc_in[2][64];
  __shared__ float loc_f_s[32][16];
  __shared__ float att_s[2][128];
  __shared__ float v_s[128];
  __shared__ float align_s[256];
  __shared__ float sred[8];

  unsigned mygen = 0;
  f32x4 zero4; zero4[0] = zero4[1] = zero4[2] = zero4[3] = 0.f;
  f32x4 acc2 = zero4;

  const int sb = wg >> 4;          // batch for s_tmp slice
  const int st0 = (wg & 15) << 4;  // t' base for s_tmp slice

#pragma unroll 1
  for (int t = 0; t < DEC_T_; ++t) {
    const int cb = t & 1, pb = cb ^ 1;
    // ================= PHASE A =================
    // (1) finish gates2(t-1): += Wih2[:,1024:1536] @ ctx_{t-1}; update h2,c2
    if (t > 0) {
      const u16* arow = wih2 + (long)grow * 1536 + 1024;
      const u16* brow = ctxg + pb * (B_ * 512) + bb * 512;
#pragma unroll
      for (int kb = 0; kb < 4; ++kb) {
        int k0 = ((wid * 4 + kb) << 5) + (q << 3);
        acc2 = __builtin_amdgcn_mfma_f32_16x16x32_bf16(
            *(const bf16x8*)(arow + k0), *(const bf16x8*)(brow + k0), acc2, 0, 0, 0);
      }
      __syncthreads();
      *(f32x4*)&red[wid][lane][0] = acc2;
      __syncthreads();
      if (tid < 64) {
        int u = tid >> 4, bi = tid & 15;
        float gi = 0, gf = 0, gg = 0, go = 0;
#pragma unroll
        for (int w = 0; w < 4; ++w) {
          gi += red[w][bi][u];
          gf += red[w][16 + bi][u];
          gg += red[w][32 + bi][u];
          go += red[w][48 + bi][u];
        }
        int unit = u0 + u;
        gi += b2f(b2[unit]); gf += b2f(b2[1024 + unit]);
        gg += b2f(b2[2048 + unit]); go += b2f(b2[3072 + unit]);
        float cold = c2g[bi * 1024 + unit];
        float cn = sigm(gf) * cold + sigm(gi) * tanh_fast(gg);
        float hn = sigm(go) * tanh_fast(cn);
        c2g[bi * 1024 + unit] = cn;
        h2g[bi * 1024 + unit] = f2b(hn);
      }
      acc2 = zero4;
    }
    // (2) location features: s_tmp[b][a][t'] = pm + dense(conv(align,cum))
    {
      if (tid < 128) {
        int i = tid & 63, ch = tid >> 6;
        int tg = st0 - 16 + i;
        float val = 0.f;
        if (tg >= 0 && tg < ENC_T_) val = (ch == 0 ? alignf : cumf)[sb * ENC_T_ + tg];
        loc_in[ch][i] = val;
      }
      __syncthreads();
#pragma unroll
      for (int rep = 0; rep < 2; ++rep) {
        int o = tid + rep * 256;
        int c = o >> 4, j = o & 15;
        float s = 0.f;
        const u16* wc = wconv + c * 62;
#pragma unroll
        for (int k = 0; k < 31; ++k) {
          s += loc_in[0][j + 1 + k] * b2f(wc[k]);
          s += loc_in[1][j + 1 + k] * b2f(wc[31 + k]);
        }
        loc_f_s[c][j] = s;
      }
      __syncthreads();
      {
        int a = tid & 127;
        const u16* wd = wdense + a * 32;
#pragma unroll 1
        for (int jj = 0; jj < 8; ++jj) {
          int j = ((tid >> 7) << 3) + jj;
          long idx = ((long)sb * ATT_ + a) * ENC_T_ + st0 + j;
          float s = pm[idx];
#pragma unroll
          for (int c = 0; c < 32; ++c) s += loc_f_s[c][j] * b2f(wd[c]);
          s_tmp[idx] = s;
        }
      }
    }
    // (3) gates1: Wih1 @ [pre_t | ctx_{t-1}] + Whh1 @ h1_{t-1}; update h1,c1
    {
      f32x4 acc1 = zero4;
      const u16* a_ih = wih1 + (long)grow * 768;
      const u16* a_hh = whh1 + (long)grow * 1024 - 768;
      const u16* b_pre = pre + ((long)t * B_ + bb) * 256;
      const u16* b_ctx = ctxg + pb * (B_ * 512) + bb * 512 - 256;
      const u16* b_h1 = h1g + pb * (B_ * 1024) + bb * 1024 - 768;
#pragma unroll 1
      for (int kb = wid * 14; kb < wid * 14 + 14; ++kb) {
        int k0 = (kb << 5) + (q << 3);
        const u16* ap = (k0 < 768) ? (a_ih + k0) : (a_hh + k0);
        const u16* bp = (k0 < 256) ? (b_pre + k0) : (k0 < 768) ? (b_ctx + k0) : (b_h1 + k0);
        acc1 = __builtin_amdgcn_mfma_f32_16x16x32_bf16(
            *(const bf16x8*)ap, *(const bf16x8*)bp, acc1, 0, 0, 0);
      }
      __syncthreads();
      *(f32x4*)&red[wid][lane][0] = acc1;
      __syncthreads();
      if (tid < 64) {
        int u = tid >> 4, bi = tid & 15;
        float gi = 0, gf = 0, gg = 0, go = 0;
#pragma unroll
        for (int w = 0; w < 4; ++w) {
          gi += red[w][bi][u];
          gf += red[w][16 + bi][u];
          gg += red[w][32 + bi][u];
          go += red[w][48 + bi][u];
        }
        int unit = u0 + u;
        gi += b2f(b1[unit]); gf += b2f(b1[1024 + unit]);
        gg += b2f(b1[2048 + unit]); go += b2f(b1[3072 + unit]);
        float cold = c1g[bi * 1024 + unit];
        float cn = sigm(gf) * cold + sigm(gi) * tanh_fast(gg);
        float hn = sigm(go) * tanh_fast(cn);
        c1g[bi * 1024 + unit] = cn;
        h1g[cb * (B_ * 1024) + bi * 1024 + unit] = f2b(hn);
      }
    }
    gbar(bar_cnt, bar_gen, mygen);
    // ================= PHASE B =================
    if (wg < B_) {
      // attention for batch wg
      const int ab = wg;
      const int len_b = lens[ab];
      {
        int a = tid & 127, h = tid >> 7;
        const u16* wr = wq + (long)a * 1024 + h * 512;
        const u16* hr = h1g + cb * (B_ * 1024) + ab * 1024 + h * 512;
        float p = 0.f;
        for (int k = 0; k < 512; k += 8) {
          bf16x8 w8 = *(const bf16x8*)(wr + k);
          bf16x8 h8 = *(const bf16x8*)(hr + k);
#pragma unroll
          for (int j = 0; j < 8; ++j) p += b2f((u16)w8[j]) * b2f((u16)h8[j]);
        }
        att_s[h][a] = p;
      }
      if (tid < 128) v_s[tid] = b2f(vv[tid]);
      __syncthreads();
      if (tid < 128) att_s[0][tid] += att_s[1][tid];
      __syncthreads();
      float e;
      {
        const float* sc = s_tmp + ((long)ab * ATT_) * ENC_T_ + tid;
        float acc = 0.f;
#pragma unroll 4
        for (int a = 0; a < 128; ++a)
          acc = fmaf(tanh_fast(sc[(long)a * ENC_T_] + att_s[0][a]), v_s[a], acc);
        e = (tid >= len_b) ? -1e9f : acc;
      }
      float mx = e;
#pragma unroll
      for (int off = 32; off; off >>= 1) mx = fmaxf(mx, __shfl_xor(mx, off));
      if (lane == 0) sred[wid] = mx;
      __syncthreads();
      mx = fmaxf(fmaxf(sred[0], sred[1]), fmaxf(sred[2], sred[3]));
      float ex = __expf(e - mx);
      float sm = ex;
#pragma unroll
      for (int off = 32; off; off >>= 1) sm += __shfl_xor(sm, off);
      if (lane == 0) sred[4 + wid] = sm;
      __syncthreads();
      sm = sred[4] + sred[5] + sred[6] + sred[7];
      float al = ex / sm;
      align_s[tid] = al;
      alignf[ab * ENC_T_ + tid] = al;
      cumf[ab * ENC_T_ + tid] += al;
      outa[((long)ab * ENC_T_ + tid) * DEC_T_ + t] = al;
      __syncthreads();
      {
        const u16* mt = mem_t + (long)ab * (ENC_T_ * ENC_D_);
        float c0 = 0.f, c1v = 0.f;
#pragma unroll 2
        for (int tp = 0; tp < ENC_T_; ++tp) {
          float av = align_s[tp];
          c0 = fmaf(av, b2f(mt[(long)tp * ENC_D_ + tid]), c0);
          c1v = fmaf(av, b2f(mt[(long)tp * ENC_D_ + tid + 256]), c1v);
        }
        ctxg[cb * (B_ * 512) + ab * 512 + tid] = f2b(c0);
        ctxg[cb * (B_ * 512) + ab * 512 + tid + 256] = f2b(c1v);
      }
    }
    if (wg >= 16 && wg < 49 && t > 0) {
      // proj(t-1): [h2_{t-1} | ctx_{t-1}] @ projW^T + b
      int tt = wg - 16, r0 = tt << 4;
      int rowp = r0 + m;
      int rowc = rowp > 512 ? 512 : rowp;
      const u16* ar = wproj + (long)rowc * 1536;
      const u16* br_h2 = h2g + bb * 1024;
      const u16* br_ctx = ctxg + pb * (B_ * 512) + bb * 512 - 1024;
      f32x4 accp = zero4;
#pragma unroll 1
      for (int kb = wid * 12; kb < wid * 12 + 12; ++kb) {
        int k0 = (kb << 5) + (q << 3);
        const u16* bp = (k0 < 1024) ? (br_h2 + k0) : (br_ctx + k0);
        accp = __builtin_amdgcn_mfma_f32_16x16x32_bf16(
            *(const bf16x8*)(ar + k0), *(const bf16x8*)bp, accp, 0, 0, 0);
      }
      __syncthreads();
      *(f32x4*)&red[wid][lane][0] = accp;
      __syncthreads();
      {
        int mm = tid >> 4, bi = tid & 15;
        int row = r0 + mm;
        if (row < FEAT_D_) {
          int l = ((mm >> 2) << 4) + bi, r = mm & 3;
          float s = red[0][l][r] + red[1][l][r] + red[2][l][r] + red[3][l][r];
          s += b2f(bproj[row]);
          outf[((long)bi * FEAT_D_ + row) * DEC_T_ + (t - 1)] = s;
        }
      }
    }
    // gates2 partial for step t: Wih2[:,0:1024] @ h1_t + Whh2 @ h2_{t-1}
    {
      const u16* a_ih = wih2 + (long)grow * 1536;
      const u16* a_hh = whh2 + (long)grow * 1024 - 1024;
      const u16* b_h1 = h1g + cb * (B_ * 1024) + bb * 1024;
      const u16* b_h2 = h2g + bb * 1024 - 1024;
#pragma unroll 1
      for (int kb = wid * 16; kb < wid * 16 + 16; ++kb) {
        int k0 = (kb << 5) + (q << 3);
        const u16* ap = (k0 < 1024) ? (a_ih + k0) : (a_hh + k0);
        const u16* bp = (k0 < 1024) ? (b_h1 + k0) : (b_h2 + k0);
        acc2 = __builtin_amdgcn_mfma_f32_16x16x32_bf16(
            *(const bf16x8*)ap, *(const bf16x8*)bp, acc2, 0, 0, 0);
      }
    }
    gbar(bar_cnt, bar_gen, mygen);
  }
  // ================= EPILOGUE: finish step 511 =================
  {
    const u16* arow = wih2 + (long)grow * 1536 + 1024;
    const u16* brow = ctxg + 1 * (B_ * 512) + bb * 512;  // ctx_511 in buffer 1
#pragma unroll
    for (int kb = 0; kb < 4; ++kb) {
      int k0 = ((wid * 4 + kb) << 5) + (q << 3);
      acc2 = __builtin_amdgcn_mfma_f32_16x16x32_bf16(
          *(const bf16x8*)(arow + k0), *(const bf16x8*)(brow + k0), acc2, 0, 0, 0);
    }
    __syncthreads();
    *(f32x4*)&red[wid][lane][0] = acc2;
    __syncthreads();
    if (tid < 64) {
      int u = tid >> 4, bi = tid & 15;
      float gi = 0, gf = 0, gg = 0, go = 0;
#pragma unroll
      for (int w = 0; w < 4; ++w) {
        gi += red[w][bi][u];
        gf += red[w][16 + bi][u];
        gg += red[w][32 + bi][u];
        go += red[w][48 + bi][u];
      }
      int unit = u0 + u;
      gi += b2f(b2[unit]); gf += b2f(b2[1024 + unit]);
      gg += b2f(b2[2048 + unit]); go += b2f(b2[3072 + unit]);
      float cold = c2g[bi * 1024 + unit];
      float cn = sigm(gf) * cold + sigm(gi) * tanh_fast(gg);
      float hn = sigm(go) * tanh_fast(cn);
      c2g[bi * 1024 + unit] = cn;
      h2g[bi * 1024 + unit] = f2b(hn);
    }
  }
  gbar(bar_cnt, bar_gen, mygen);
  if (wg >= 16 && wg < 49) {
    int tt = wg - 16, r0 = tt << 4;
    int rowp = r0 + m;
    int rowc = rowp > 512 ? 512 : rowp;
    const u16* ar = wproj + (long)rowc * 1536;
    const u16* br_h2 = h2g + bb * 1024;
    const u16* br_ctx = ctxg + 1 * (B_ * 512) + bb * 512 - 1024;
    f32x4 accp; accp[0] = accp[1] = accp[2] = accp[3] = 0.f;
#pragma unroll 1
    for (int kb = wid * 12; kb < wid * 12 + 12; ++kb) {
      int k0 = (kb << 5) + (q << 3);
      const u16* bp = (k0 < 1024) ? (br_h2 + k0) : (br_ctx + k0);
      accp = __builtin_amdgcn_mfma_f32_16x16x32_bf16(
          *(const bf16x8*)(ar + k0), *(const bf16x8*)bp, accp, 0, 0, 0);
    }
    __syncthreads();
    *(f32x4*)&red[wid][lane][0] = accp;
    __syncthreads();
    {
      int mm = tid >> 4, bi = tid & 15;
      int row = r0 + mm;
      if (row < FEAT_D_) {
        int l = ((mm >> 2) << 4) + bi, r = mm & 3;
        float s = red[0][l][r] + red[1][l][r] + red[2][l][r] + red[3][l][r];
        s += b2f(bproj[row]);
        outf[((long)bi * FEAT_D_ + row) * DEC_T_ + 511] = s;
      }
    }
  }
}

extern "C" void kernel_launch(void* const* d_in, const int* in_sizes, int n_in,
                              void* d_out, int out_size, void* d_ws, size_t ws_size,
                              hipStream_t stream) {
  const void* enc   = d_in[0];
  const void* feats = d_in[2];
  const void* go    = d_in[3];
  const void* w0    = d_in[4];
  const void* w1    = d_in[5];

  float* outf = (float*)d_out;                         // [16][513][512] fp32
  float* outa = outf + (size_t)B_ * FEAT_D_ * DEC_T_;  // [16][256][512] fp32

  char* ws = (char*)d_ws;
  size_t off = 0;
  auto take = [&](size_t bytes) { char* p = ws + off; off += (bytes + 255) & ~size_t(255); return p; };
  int*   flag   = (int*)take(256);
  int*   lens_d = (int*)take(256);
  u16*   pre    = (u16*)take((size_t)DEC_T_ * B_ * 256 * 2);
  u16*   mem_t  = (u16*)take((size_t)B_ * ENC_T_ * ENC_D_ * 2);
  float* pm     = (float*)take((size_t)B_ * ATT_ * ENC_T_ * 4);
  float* s_tmp  = (float*)take((size_t)B_ * ATT_ * ENC_T_ * 4);
  u16*   h1g    = (u16*)take((size_t)2 * B_ * 1024 * 2);
  u16*   h2g    = (u16*)take((size_t)B_ * 1024 * 2);
  u16*   ctxg   = (u16*)take((size_t)2 * B_ * 512 * 2);
  float* c1g    = (float*)take((size_t)B_ * 1024 * 4);
  float* c2g    = (float*)take((size_t)B_ * 1024 * 4);
  float* alignf = (float*)take((size_t)B_ * ENC_T_ * 4);
  float* cumf   = (float*)take((size_t)B_ * ENC_T_ * 4);
  unsigned* bar_cnt = (unsigned*)take(256);
  unsigned* bar_gen = (unsigned*)take(256);
  // bf16 copies of decoder weights:
  u16* wih1   = (u16*)take((size_t)4096 * 768 * 2);
  u16* whh1   = (u16*)take((size_t)4096 * 1024 * 2);
  u16* b1c    = (u16*)take((size_t)4096 * 2);
  u16* wih2   = (u16*)take((size_t)4096 * 1536 * 2);
  u16* whh2   = (u16*)take((size_t)4096 * 1024 * 2);
  u16* b2c    = (u16*)take((size_t)4096 * 2);
  u16* wqc    = (u16*)take((size_t)128 * 1024 * 2);
  u16* wconvc = (u16*)take((size_t)32 * 2 * 31 * 2);
  u16* wdensec= (u16*)take((size_t)128 * 32 * 2);
  u16* vvc    = (u16*)take((size_t)128 * 2);
  u16* wprojc = (u16*)take((size_t)513 * 1536 * 2);
  u16* bprojc = (u16*)take((size_t)513 * 2);

  k_detect<<<1, 256, 0, stream>>>((const u16*)d_in[4], flag);
  k_lens<<<1, 64, 0, stream>>>(d_in[1], lens_d);

  struct CvtJob { const void* src; u16* dst; int n; };
  const CvtJob jobs[12] = {
      {d_in[6],  wih1,   4096 * 768},
      {d_in[7],  whh1,   4096 * 1024},
      {d_in[8],  b1c,    4096},
      {d_in[9],  wih2,   4096 * 1536},
      {d_in[10], whh2,   4096 * 1024},
      {d_in[11], b2c,    4096},
      {d_in[12], wqc,    128 * 1024},
      {d_in[14], wconvc, 32 * 2 * 31},
      {d_in[15], wdensec, 128 * 32},
      {d_in[16], vvc,    128},
      {d_in[17], wprojc, 513 * 1536},
      {d_in[18], bprojc, 513},
  };
  for (int i = 0; i < 12; ++i) {
    int blocks = (jobs[i].n + 255) / 256;
    if (blocks > 512) blocks = 512;
    k_cvt<<<blocks, 256, 0, stream>>>(jobs[i].src, jobs[i].dst, jobs[i].n, flag);
  }

  k_init<<<32, 256, 0, stream>>>(h1g, h2g, ctxg, c1g, c2g, alignf, cumf, bar_cnt, bar_gen);
  k_prenet<<<DEC_T_, 256, 0, stream>>>(feats, go, w0, w1, pre, flag);
  k_mem<<<256, 256, 0, stream>>>(enc, d_in[13], mem_t, pm, flag);
  k_main<<<NWG_, 256, 0, stream>>>(wih1, whh1, b1c, wih2, whh2, b2c, wqc, wconvc, wdensec,
                                   vvc, wprojc, bprojc, lens_d, pre, mem_t, pm, s_tmp,
                                   h1g, h2g, ctxg, c1g, c2g, alignf, cumf,
                                   bar_cnt, bar_gen, outf, outa);
}

// Round 7
// 61761.688 us; speedup vs baseline: 3.6788x; 1.7249x over previous
//
#include <hip/hip_runtime.h>

#define B_ 16
#define ENC_D_ 512
#define ENC_T_ 256
#define FEAT_D_ 513
#define DEC_T_ 512
#define ATT_ 128
#define NWG_ 256

typedef unsigned short u16;
typedef __attribute__((ext_vector_type(8))) short bf16x8;
typedef __attribute__((ext_vector_type(4))) float f32x4;

// ---- LDS arena offsets (bytes) ----
#define S_WIH1 0            // [16][776] u16  (768 + 8 pad)
#define S_WHH1 24832        // [16][1032] u16
#define S_WIH2 57856        // [16][1544] u16
#define S_WHH2 107264       // [16][1032] u16
#define S_RED  140288       // float[2048]  (as [4][64][4] MFMA-reduce, or [4][512] ctx partials)
#define S_ATT  148480       // float[2][128]
#define S_VS   149504       // float[128]
#define S_ALN  150016       // float[256]
#define S_LIN  151040       // float[2][64]
#define S_LF   151552       // float[32][16]
#define S_SRED 153600       // float[8]
#define LDS_BYTES 153632

__device__ __forceinline__ float b2f(u16 x) {
  unsigned u = ((unsigned)x) << 16;
  return __builtin_bit_cast(float, u);
}
__device__ __forceinline__ u16 f2b(float f) {
  unsigned u = __builtin_bit_cast(unsigned, f);
  u += 0x7FFFu + ((u >> 16) & 1u);
  return (u16)(u >> 16);
}
__device__ __forceinline__ float ldin(const void* p, long i, bool f32) {
  return f32 ? ((const float*)p)[i] : b2f(((const u16*)p)[i]);
}
__device__ __forceinline__ float sigm(float x) {
  return __builtin_amdgcn_rcpf(1.f + __expf(-x));
}
__device__ __forceinline__ float tanh_fast(float x) {
  float e = __expf(2.f * x);
  return 1.f - 2.f * __builtin_amdgcn_rcpf(e + 1.f);
}

__device__ __forceinline__ void gbar(unsigned* cnt, unsigned* gen, unsigned& mygen) {
  __threadfence();
  __syncthreads();
  ++mygen;
  if (threadIdx.x == 0) {
    if (__hip_atomic_fetch_add(cnt, 1u, __ATOMIC_ACQ_REL, __HIP_MEMORY_SCOPE_AGENT) == NWG_ - 1u) {
      __hip_atomic_store(cnt, 0u, __ATOMIC_RELAXED, __HIP_MEMORY_SCOPE_AGENT);
      __hip_atomic_store(gen, mygen, __ATOMIC_RELEASE, __HIP_MEMORY_SCOPE_AGENT);
    } else {
      while (__hip_atomic_load(gen, __ATOMIC_RELAXED, __HIP_MEMORY_SCOPE_AGENT) < mygen)
        __builtin_amdgcn_s_sleep(1);
    }
  }
  __syncthreads();
  __threadfence();
}

// float dtype detect: 0 = bf16 inputs, 1 = fp32 inputs
__global__ void k_detect(const u16* __restrict__ w, int* flag) {
  __shared__ int cnt;
  if (threadIdx.x == 0) cnt = 0;
  __syncthreads();
  int c = 0;
  for (int i = threadIdx.x; i < 512; i += 256) {
    u16 v = w[2 * i];
    int e = (v >> 7) & 0xFF;
    if (e >= 80 && e <= 140) c++;
  }
  atomicAdd(&cnt, c);
  __syncthreads();
  if (threadIdx.x == 0) *flag = (cnt >= 384) ? 0 : 1;
}

// encoding_lengths format detect (int32 is the real format; kept for safety)
__global__ void k_lens(const void* __restrict__ raw, int* __restrict__ lens_out) {
  if (threadIdx.x != 0 || blockIdx.x != 0) return;
  const int* i32 = (const int*)raw;
  const long long* i64 = (const long long*)raw;
  const float* f32 = (const float*)raw;
  const double* f64 = (const double*)raw;
  bool ok;
  ok = true;
  for (int b = 0; b < B_; ++b) { int v = i32[b]; if (v < 1 || v > ENC_T_) ok = false; }
  if (ok) { for (int b = 0; b < B_; ++b) lens_out[b] = i32[b]; return; }
  ok = true;
  for (int b = 0; b < B_; ++b) { long long v = i64[b]; if (v < 1 || v > ENC_T_) ok = false; }
  if (ok) { for (int b = 0; b < B_; ++b) lens_out[b] = (int)i64[b]; return; }
  ok = true;
  for (int b = 0; b < B_; ++b) { float x = f32[b]; if (!(x >= 1.f && x <= 256.f && x == floorf(x))) ok = false; }
  if (ok) { for (int b = 0; b < B_; ++b) lens_out[b] = (int)f32[b]; return; }
  ok = true;
  for (int b = 0; b < B_; ++b) { double x = f64[b]; if (!(x >= 1.0 && x <= 256.0 && x == floor(x))) ok = false; }
  if (ok) { for (int b = 0; b < B_; ++b) lens_out[b] = (int)f64[b]; return; }
  for (int b = 0; b < B_; ++b) {
    int v = i32[b];
    lens_out[b] = v < 1 ? 1 : (v > ENC_T_ ? ENC_T_ : v);
  }
}

// convert one tensor to bf16 in ws
__global__ void k_cvt(const void* __restrict__ src, u16* __restrict__ dst, int n,
                      const int* __restrict__ flag) {
  bool f32 = (*flag) != 0;
  int stride = blockDim.x * gridDim.x;
  for (int i = threadIdx.x + blockIdx.x * blockDim.x; i < n; i += stride)
    dst[i] = f32 ? f2b(((const float*)src)[i]) : ((const u16*)src)[i];
}

// init: zero states, set align0/cum0, barrier vars
__global__ void k_init(u16* h1g, u16* h2g, u16* ctxg, float* c1g, float* c2g,
                       float* alignf, float* cumf, unsigned* bar_cnt, unsigned* bar_gen) {
  int tid = threadIdx.x + blockIdx.x * blockDim.x;
  int stride = blockDim.x * gridDim.x;
  for (int i = tid; i < 2 * B_ * 1024; i += stride) h1g[i] = 0;
  for (int i = tid; i < B_ * 1024; i += stride) h2g[i] = 0;
  for (int i = tid; i < 2 * B_ * 512; i += stride) ctxg[i] = 0;
  for (int i = tid; i < B_ * 1024; i += stride) { c1g[i] = 0.f; c2g[i] = 0.f; }
  for (int i = tid; i < B_ * ENC_T_; i += stride) {
    float v = ((i & (ENC_T_ - 1)) == 0) ? 1.f : 0.f;
    alignf[i] = v; cumf[i] = v;
  }
  if (tid == 0) { *bar_cnt = 0u; *bar_gen = 0u; }
}

// prenet for all timesteps (teacher-forced, recurrence-free), bf16 out
__global__ __launch_bounds__(256) void k_prenet(const void* __restrict__ feats,
                                                const void* __restrict__ go,
                                                const void* __restrict__ w0,
                                                const void* __restrict__ w1,
                                                u16* __restrict__ pre,
                                                const int* __restrict__ flag) {
  const bool f32 = (*flag) != 0;
  int t = blockIdx.x, tid = threadIdx.x;
  __shared__ __align__(16) float din[FEAT_D_][16];
  __shared__ __align__(16) float o1[256][16];
  for (int idx = tid; idx < 16 * FEAT_D_; idx += 256) {
    int f = idx >> 4, b = idx & 15;
    float v = (t == 0) ? ldin(go, f, f32)
                       : ldin(feats, ((long)b * FEAT_D_ + f) * DEC_T_ + (t - 1), f32);
    din[f][b] = v;
  }
  __syncthreads();
  float acc[16];
#pragma unroll
  for (int b = 0; b < 16; ++b) acc[b] = 0.f;
  for (int f = 0; f < FEAT_D_; ++f) {
    float w = ldin(w0, (long)tid * FEAT_D_ + f, f32);
#pragma unroll
    for (int b = 0; b < 16; ++b) acc[b] += w * din[f][b];
  }
#pragma unroll
  for (int b = 0; b < 16; ++b) o1[tid][b] = fmaxf(acc[b], 0.f);
  __syncthreads();
#pragma unroll
  for (int b = 0; b < 16; ++b) acc[b] = 0.f;
  for (int r1 = 0; r1 < 256; ++r1) {
    float w = ldin(w1, (long)tid * 256 + r1, f32);
#pragma unroll
    for (int b = 0; b < 16; ++b) acc[b] += w * o1[r1][b];
  }
#pragma unroll
  for (int b = 0; b < 16; ++b)
    pre[((long)t * 16 + b) * 256 + tid] = f2b(fmaxf(acc[b], 0.f));
}

// encoder transpose (bf16) + processed-memory (fp32, layout [b][t'][a])
__global__ __launch_bounds__(256) void k_mem(const void* __restrict__ enc,
                                             const void* __restrict__ wmem,
                                             u16* __restrict__ mem_t,
                                             float* __restrict__ pm,
                                             const int* __restrict__ flag) {
  const bool f32 = (*flag) != 0;
  int b = blockIdx.x >> 4, tc = blockIdx.x & 15;
  int t0 = tc * 16, tid = threadIdx.x;
  __shared__ __align__(16) float et[16][ENC_D_];
  for (int idx = tid; idx < ENC_D_ * 16; idx += 256) {
    int d = idx >> 4, i = idx & 15;
    et[i][d] = ldin(enc, ((long)b * ENC_D_ + d) * ENC_T_ + t0 + i, f32);
  }
  __syncthreads();
  for (int idx = tid; idx < 16 * ENC_D_; idx += 256) {
    int i = idx >> 9, d = idx & 511;
    mem_t[((long)b * ENC_T_ + t0 + i) * ENC_D_ + d] = f2b(et[i][d]);
  }
  int a = tid & 127;
#pragma unroll 1
  for (int jj = 0; jj < 8; ++jj) {
    int i = ((tid >> 7) << 3) + jj;
    float s = 0.f;
    for (int d = 0; d < ENC_D_; ++d)
      s += ldin(wmem, (long)a * ENC_D_ + d, f32) * et[i][d];
    pm[((long)b * ENC_T_ + t0 + i) * ATT_ + a] = s;
  }
}

// ---------------- persistent decoder: LDS-resident weights, bf16 MFMA ----------------
__global__ __launch_bounds__(256) void k_main(
    const u16* __restrict__ wih1, const u16* __restrict__ whh1, const u16* __restrict__ b1,
    const u16* __restrict__ wih2, const u16* __restrict__ whh2, const u16* __restrict__ b2,
    const u16* __restrict__ wq, const u16* __restrict__ wconv, const u16* __restrict__ wdense,
    const u16* __restrict__ vv, const u16* __restrict__ wproj, const u16* __restrict__ bproj,
    const int* __restrict__ lens,
    const u16* __restrict__ pre, const u16* __restrict__ mem_t, const float* __restrict__ pm,
    float* s_tmp, u16* h1g, u16* h2g, u16* ctxg, float* c1g, float* c2g,
    float* alignf, float* cumf, unsigned* bar_cnt, unsigned* bar_gen,
    float* outf, float* outa) {
  extern __shared__ __align__(16) char smem[];
  u16* s_wih1 = (u16*)(smem + S_WIH1);
  u16* s_whh1 = (u16*)(smem + S_WHH1);
  u16* s_wih2 = (u16*)(smem + S_WIH2);
  u16* s_whh2 = (u16*)(smem + S_WHH2);
  float* red_f = (float*)(smem + S_RED);
  float (*red)[64][4] = (float(*)[64][4])red_f;
  float (*att_s)[128] = (float(*)[128])(smem + S_ATT);
  float* v_s = (float*)(smem + S_VS);
  float* align_s = (float*)(smem + S_ALN);
  float (*loc_in)[64] = (float(*)[64])(smem + S_LIN);
  float (*loc_f_s)[16] = (float(*)[16])(smem + S_LF);
  float* sred = (float*)(smem + S_SRED);

  const int wg = blockIdx.x, tid = threadIdx.x;
  const int wid = tid >> 6, lane = tid & 63;
  const int m = lane & 15, q = lane >> 4;
  const int u0 = wg << 2;
  const int bb = m;  // B-frag batch index

  // ---- stage this WG's weight rows into LDS (once; weights are step-invariant) ----
  for (int r = 0; r < 4; ++r) {
    int m2 = wid * 4 + r;
    int growr = ((m2 >> 2) << 10) + u0 + (m2 & 3);
    {
      const u16* s = wih1 + (long)growr * 768; u16* d = s_wih1 + m2 * 776;
      for (int c = lane; c < 96; c += 64) *(bf16x8*)(d + c * 8) = *(const bf16x8*)(s + c * 8);
    }
    {
      const u16* s = whh1 + (long)growr * 1024; u16* d = s_whh1 + m2 * 1032;
      for (int c = lane; c < 128; c += 64) *(bf16x8*)(d + c * 8) = *(const bf16x8*)(s + c * 8);
    }
    {
      const u16* s = wih2 + (long)growr * 1536; u16* d = s_wih2 + m2 * 1544;
      for (int c = lane; c < 192; c += 64) *(bf16x8*)(d + c * 8) = *(const bf16x8*)(s + c * 8);
    }
    {
      const u16* s = whh2 + (long)growr * 1024; u16* d = s_whh2 + m2 * 1032;
      for (int c = lane; c < 128; c += 64) *(bf16x8*)(d + c * 8) = *(const bf16x8*)(s + c * 8);
    }
  }
  __syncthreads();

  unsigned mygen = 0;
  f32x4 zero4; zero4[0] = zero4[1] = zero4[2] = zero4[3] = 0.f;
  f32x4 acc2 = zero4;

  const int sb = wg >> 4;          // batch for s_tmp slice
  const int st0 = (wg & 15) << 4;  // t' base for s_tmp slice
  const u16* a1_ih = s_wih1 + m * 776;
  const u16* a1_hh = s_whh1 + m * 1032;
  const u16* a2_ih = s_wih2 + m * 1544;
  const u16* a2_hh = s_whh2 + m * 1032;

#pragma unroll 1
  for (int t = 0; t < DEC_T_; ++t) {
    const int cb = t & 1, pb = cb ^ 1;
    // ================= PHASE A =================
    // (1) finish gates2(t-1): += Wih2[:,1024:1536] @ ctx_{t-1}; update h2,c2
    if (t > 0) {
      const u16* brow = ctxg + pb * (B_ * 512) + bb * 512;
#pragma unroll
      for (int kb = 0; kb < 4; ++kb) {
        int k0 = ((wid * 4 + kb) << 5) + (q << 3);
        acc2 = __builtin_amdgcn_mfma_f32_16x16x32_bf16(
            *(const bf16x8*)(a2_ih + 1024 + k0), *(const bf16x8*)(brow + k0), acc2, 0, 0, 0);
      }
      __syncthreads();
      *(f32x4*)&red[wid][lane][0] = acc2;
      __syncthreads();
      if (tid < 64) {
        int u = tid >> 4, bi = tid & 15;
        float gi = 0, gf = 0, gg = 0, go = 0;
#pragma unroll
        for (int w = 0; w < 4; ++w) {
          gi += red[w][bi][u];
          gf += red[w][16 + bi][u];
          gg += red[w][32 + bi][u];
          go += red[w][48 + bi][u];
        }
        int unit = u0 + u;
        gi += b2f(b2[unit]); gf += b2f(b2[1024 + unit]);
        gg += b2f(b2[2048 + unit]); go += b2f(b2[3072 + unit]);
        float cold = c2g[bi * 1024 + unit];
        float cn = sigm(gf) * cold + sigm(gi) * tanh_fast(gg);
        float hn = sigm(go) * tanh_fast(cn);
        c2g[bi * 1024 + unit] = cn;
        h2g[bi * 1024 + unit] = f2b(hn);
      }
      acc2 = zero4;
    }
    // (2) location features: s_tmp[b][t'][a] = pm + dense(conv(align,cum))
    {
      if (tid < 128) {
        int i = tid & 63, ch = tid >> 6;
        int tg = st0 - 16 + i;
        float val = 0.f;
        if (tg >= 0 && tg < ENC_T_) val = (ch == 0 ? alignf : cumf)[sb * ENC_T_ + tg];
        loc_in[ch][i] = val;
      }
      __syncthreads();
#pragma unroll
      for (int rep = 0; rep < 2; ++rep) {
        int o = tid + rep * 256;
        int c = o >> 4, j = o & 15;
        float s = 0.f;
        const u16* wc = wconv + c * 62;
#pragma unroll
        for (int k = 0; k < 31; ++k) {
          s += loc_in[0][j + 1 + k] * b2f(wc[k]);
          s += loc_in[1][j + 1 + k] * b2f(wc[31 + k]);
        }
        loc_f_s[c][j] = s;
      }
      __syncthreads();
      {
        int a = tid & 127;
        const u16* wd = wdense + a * 32;
#pragma unroll 1
        for (int jj = 0; jj < 8; ++jj) {
          int j = ((tid >> 7) << 3) + jj;
          long idx = ((long)sb * ENC_T_ + st0 + j) * ATT_ + a;
          float s = pm[idx];
#pragma unroll
          for (int c = 0; c < 32; ++c) s += loc_f_s[c][j] * b2f(wd[c]);
          s_tmp[idx] = s;
        }
      }
    }
    // (3) gates1: Wih1 @ [pre_t | ctx_{t-1}] + Whh1 @ h1_{t-1}; update h1,c1
    {
      f32x4 acc1 = zero4;
      const u16* b_pre = pre + ((long)t * B_ + bb) * 256;
      const u16* b_ctx = ctxg + pb * (B_ * 512) + bb * 512 - 256;
      const u16* b_h1 = h1g + pb * (B_ * 1024) + bb * 1024 - 768;
#pragma unroll 1
      for (int kb = wid * 14; kb < wid * 14 + 14; ++kb) {
        int k0 = (kb << 5) + (q << 3);
        const u16* ap = (k0 < 768) ? (a1_ih + k0) : (a1_hh + (k0 - 768));
        const u16* bp = (k0 < 256) ? (b_pre + k0) : (k0 < 768) ? (b_ctx + k0) : (b_h1 + k0);
        acc1 = __builtin_amdgcn_mfma_f32_16x16x32_bf16(
            *(const bf16x8*)ap, *(const bf16x8*)bp, acc1, 0, 0, 0);
      }
      __syncthreads();
      *(f32x4*)&red[wid][lane][0] = acc1;
      __syncthreads();
      if (tid < 64) {
        int u = tid >> 4, bi = tid & 15;
        float gi = 0, gf = 0, gg = 0, go = 0;
#pragma unroll
        for (int w = 0; w < 4; ++w) {
          gi += red[w][bi][u];
          gf += red[w][16 + bi][u];
          gg += red[w][32 + bi][u];
          go += red[w][48 + bi][u];
        }
        int unit = u0 + u;
        gi += b2f(b1[unit]); gf += b2f(b1[1024 + unit]);
        gg += b2f(b1[2048 + unit]); go += b2f(b1[3072 + unit]);
        float cold = c1g[bi * 1024 + unit];
        float cn = sigm(gf) * cold + sigm(gi) * tanh_fast(gg);
        float hn = sigm(go) * tanh_fast(cn);
        c1g[bi * 1024 + unit] = cn;
        h1g[cb * (B_ * 1024) + bi * 1024 + unit] = f2b(hn);
      }
    }
    gbar(bar_cnt, bar_gen, mygen);
    // ================= PHASE B =================
    if (wg < B_) {
      // attention for batch wg
      const int ab = wg;
      const int len_b = lens[ab];
      {
        int a = tid & 127, h = tid >> 7;
        const u16* wr = wq + (long)a * 1024 + h * 512;
        const u16* hr = h1g + cb * (B_ * 1024) + ab * 1024 + h * 512;
        float p = 0.f;
        for (int k = 0; k < 512; k += 8) {
          bf16x8 w8 = *(const bf16x8*)(wr + k);
          bf16x8 h8 = *(const bf16x8*)(hr + k);
#pragma unroll
          for (int j = 0; j < 8; ++j) p += b2f((u16)w8[j]) * b2f((u16)h8[j]);
        }
        att_s[h][a] = p;
      }
      if (tid < 128) v_s[tid] = b2f(vv[tid]);
      __syncthreads();
      if (tid < 128) att_s[0][tid] += att_s[1][tid];
      __syncthreads();
      float e;
      {
        const float* sc = s_tmp + ((long)ab * ENC_T_ + tid) * ATT_;
        float acc = 0.f;
#pragma unroll 4
        for (int a = 0; a < 128; ++a)
          acc = fmaf(tanh_fast(sc[a] + att_s[0][a]), v_s[a], acc);
        e = (tid >= len_b) ? -1e9f : acc;
      }
      float mx = e;
#pragma unroll
      for (int off = 32; off; off >>= 1) mx = fmaxf(mx, __shfl_xor(mx, off));
      if (lane == 0) sred[wid] = mx;
      __syncthreads();
      mx = fmaxf(fmaxf(sred[0], sred[1]), fmaxf(sred[2], sred[3]));
      float ex = __expf(e - mx);
      float sm = ex;
#pragma unroll
      for (int off = 32; off; off >>= 1) sm += __shfl_xor(sm, off);
      if (lane == 0) sred[4 + wid] = sm;
      __syncthreads();
      sm = sred[4] + sred[5] + sred[6] + sred[7];
      float al = ex / sm;
      align_s[tid] = al;
      alignf[ab * ENC_T_ + tid] = al;
      cumf[ab * ENC_T_ + tid] += al;
      outa[((long)ab * ENC_T_ + tid) * DEC_T_ + t] = al;
      __syncthreads();
      {
        // ctx = align @ mem_t : 4 waves x 64 t' each, 8 dims/thread, LDS reduce
        int g = tid & 63, qd = tid >> 6;
        const u16* mt = mem_t + (long)ab * (ENC_T_ * ENC_D_) + g * 8;
        float a8[8];
#pragma unroll
        for (int j = 0; j < 8; ++j) a8[j] = 0.f;
#pragma unroll 2
        for (int tp = qd * 64; tp < qd * 64 + 64; ++tp) {
          float av = align_s[tp];
          bf16x8 m8 = *(const bf16x8*)(mt + (long)tp * ENC_D_);
#pragma unroll
          for (int j = 0; j < 8; ++j) a8[j] = fmaf(av, b2f((u16)m8[j]), a8[j]);
        }
#pragma unroll
        for (int j = 0; j < 8; ++j) red_f[qd * 512 + g * 8 + j] = a8[j];
        __syncthreads();
        for (int d = tid; d < 512; d += 256) {
          float s = red_f[d] + red_f[512 + d] + red_f[1024 + d] + red_f[1536 + d];
          ctxg[cb * (B_ * 512) + ab * 512 + d] = f2b(s);
        }
      }
    }
    if (wg >= 16 && wg < 49 && t > 0) {
      // proj(t-1): [h2_{t-1} | ctx_{t-1}] @ projW^T + b
      int tt = wg - 16, r0 = tt << 4;
      int rowp = r0 + m;
      int rowc = rowp > 512 ? 512 : rowp;
      const u16* ar = wproj + (long)rowc * 1536;
      const u16* br_h2 = h2g + bb * 1024;
      const u16* br_ctx = ctxg + pb * (B_ * 512) + bb * 512 - 1024;
      f32x4 accp = zero4;
#pragma unroll 1
      for (int kb = wid * 12; kb < wid * 12 + 12; ++kb) {
        int k0 = (kb << 5) + (q << 3);
        const u16* bp = (k0 < 1024) ? (br_h2 + k0) : (br_ctx + k0);
        accp = __builtin_amdgcn_mfma_f32_16x16x32_bf16(
            *(const bf16x8*)(ar + k0), *(const bf16x8*)bp, accp, 0, 0, 0);
      }
      __syncthreads();
      *(f32x4*)&red[wid][lane][0] = accp;
      __syncthreads();
      {
        int mm = tid >> 4, bi = tid & 15;
        int row = r0 + mm;
        if (row < FEAT_D_) {
          int l = ((mm >> 2) << 4) + bi, r = mm & 3;
          float s = red[0][l][r] + red[1][l][r] + red[2][l][r] + red[3][l][r];
          s += b2f(bproj[row]);
          outf[((long)bi * FEAT_D_ + row) * DEC_T_ + (t - 1)] = s;
        }
      }
    }
    // gates2 partial for step t: Wih2[:,0:1024] @ h1_t + Whh2 @ h2_{t-1}
    {
      const u16* b_h1 = h1g + cb * (B_ * 1024) + bb * 1024;
      const u16* b_h2 = h2g + bb * 1024 - 1024;
#pragma unroll 1
      for (int kb = wid * 16; kb < wid * 16 + 16; ++kb) {
        int k0 = (kb << 5) + (q << 3);
        const u16* ap = (k0 < 1024) ? (a2_ih + k0) : (a2_hh + (k0 - 1024));
        const u16* bp = (k0 < 1024) ? (b_h1 + k0) : (b_h2 + k0);
        acc2 = __builtin_amdgcn_mfma_f32_16x16x32_bf16(
            *(const bf16x8*)ap, *(const bf16x8*)bp, acc2, 0, 0, 0);
      }
    }
    gbar(bar_cnt, bar_gen, mygen);
  }
  // ================= EPILOGUE: finish step 511 =================
  {
    const u16* brow = ctxg + 1 * (B_ * 512) + bb * 512;  // ctx_511 in buffer 1
#pragma unroll
    for (int kb = 0; kb < 4; ++kb) {
      int k0 = ((wid * 4 + kb) << 5) + (q << 3);
      acc2 = __builtin_amdgcn_mfma_f32_16x16x32_bf16(
          *(const bf16x8*)(a2_ih + 1024 + k0), *(const bf16x8*)(brow + k0), acc2, 0, 0, 0);
    }
    __syncthreads();
    *(f32x4*)&red[wid][lane][0] = acc2;
    __syncthreads();
    if (tid < 64) {
      int u = tid >> 4, bi = tid & 15;
      float gi = 0, gf = 0, gg = 0, go = 0;
#pragma unroll
      for (int w = 0; w < 4; ++w) {
        gi += red[w][bi][u];
        gf += red[w][16 + bi][u];
        gg += red[w][32 + bi][u];
        go += red[w][48 + bi][u];
      }
      int unit = u0 + u;
      gi += b2f(b2[unit]); gf += b2f(b2[1024 + unit]);
      gg += b2f(b2[2048 + unit]); go += b2f(b2[3072 + unit]);
      float cold = c2g[bi * 1024 + unit];
      float cn = sigm(gf) * cold + sigm(gi) * tanh_fast(gg);
      float hn = sigm(go) * tanh_fast(cn);
      c2g[bi * 1024 + unit] = cn;
      h2g[bi * 1024 + unit] = f2b(hn);
    }
  }
  gbar(bar_cnt, bar_gen, mygen);
  if (wg >= 16 && wg < 49) {
    int tt = wg - 16, r0 = tt << 4;
    int rowp = r0 + m;
    int rowc = rowp > 512 ? 512 : rowp;
    const u16* ar = wproj + (long)rowc * 1536;
    const u16* br_h2 = h2g + bb * 1024;
    const u16* br_ctx = ctxg + 1 * (B_ * 512) + bb * 512 - 1024;
    f32x4 accp; accp[0] = accp[1] = accp[2] = accp[3] = 0.f;
#pragma unroll 1
    for (int kb = wid * 12; kb < wid * 12 + 12; ++kb) {
      int k0 = (kb << 5) + (q << 3);
      const u16* bp = (k0 < 1024) ? (br_h2 + k0) : (br_ctx + k0);
      accp = __builtin_amdgcn_mfma_f32_16x16x32_bf16(
          *(const bf16x8*)(ar + k0), *(const bf16x8*)bp, accp, 0, 0, 0);
    }
    __syncthreads();
    *(f32x4*)&red[wid][lane][0] = accp;
    __syncthreads();
    {
      int mm = tid >> 4, bi = tid & 15;
      int row = r0 + mm;
      if (row < FEAT_D_) {
        int l = ((mm >> 2) << 4) + bi, r = mm & 3;
        float s = red[0][l][r] + red[1][l][r] + red[2][l][r] + red[3][l][r];
        s += b2f(bproj[row]);
        outf[((long)bi * FEAT_D_ + row) * DEC_T_ + 511] = s;
      }
    }
  }
}

extern "C" void kernel_launch(void* const* d_in, const int* in_sizes, int n_in,
                              void* d_out, int out_size, void* d_ws, size_t ws_size,
                              hipStream_t stream) {
  const void* enc   = d_in[0];
  const void* feats = d_in[2];
  const void* go    = d_in[3];
  const void* w0    = d_in[4];
  const void* w1    = d_in[5];

  float* outf = (float*)d_out;                         // [16][513][512] fp32
  float* outa = outf + (size_t)B_ * FEAT_D_ * DEC_T_;  // [16][256][512] fp32

  char* ws = (char*)d_ws;
  size_t off = 0;
  auto take = [&](size_t bytes) { char* p = ws + off; off += (bytes + 255) & ~size_t(255); return p; };
  int*   flag   = (int*)take(256);
  int*   lens_d = (int*)take(256);
  u16*   pre    = (u16*)take((size_t)DEC_T_ * B_ * 256 * 2);
  u16*   mem_t  = (u16*)take((size_t)B_ * ENC_T_ * ENC_D_ * 2);
  float* pm     = (float*)take((size_t)B_ * ENC_T_ * ATT_ * 4);
  float* s_tmp  = (float*)take((size_t)B_ * ENC_T_ * ATT_ * 4);
  u16*   h1g    = (u16*)take((size_t)2 * B_ * 1024 * 2);
  u16*   h2g    = (u16*)take((size_t)B_ * 1024 * 2);
  u16*   ctxg   = (u16*)take((size_t)2 * B_ * 512 * 2);
  float* c1g    = (float*)take((size_t)B_ * 1024 * 4);
  float* c2g    = (float*)take((size_t)B_ * 1024 * 4);
  float* alignf = (float*)take((size_t)B_ * ENC_T_ * 4);
  float* cumf   = (float*)take((size_t)B_ * ENC_T_ * 4);
  unsigned* bar_cnt = (unsigned*)take(256);
  unsigned* bar_gen = (unsigned*)take(256);
  // bf16 copies of decoder weights:
  u16* wih1   = (u16*)take((size_t)4096 * 768 * 2);
  u16* whh1   = (u16*)take((size_t)4096 * 1024 * 2);
  u16* b1c    = (u16*)take((size_t)4096 * 2);
  u16* wih2   = (u16*)take((size_t)4096 * 1536 * 2);
  u16* whh2   = (u16*)take((size_t)4096 * 1024 * 2);
  u16* b2c    = (u16*)take((size_t)4096 * 2);
  u16* wqc    = (u16*)take((size_t)128 * 1024 * 2);
  u16* wconvc = (u16*)take((size_t)32 * 2 * 31 * 2);
  u16* wdensec= (u16*)take((size_t)128 * 32 * 2);
  u16* vvc    = (u16*)take((size_t)128 * 2);
  u16* wprojc = (u16*)take((size_t)513 * 1536 * 2);
  u16* bprojc = (u16*)take((size_t)513 * 2);

  k_detect<<<1, 256, 0, stream>>>((const u16*)d_in[4], flag);
  k_lens<<<1, 64, 0, stream>>>(d_in[1], lens_d);

  struct CvtJob { const void* src; u16* dst; int n; };
  const CvtJob jobs[12] = {
      {d_in[6],  wih1,   4096 * 768},
      {d_in[7],  whh1,   4096 * 1024},
      {d_in[8],  b1c,    4096},
      {d_in[9],  wih2,   4096 * 1536},
      {d_in[10], whh2,   4096 * 1024},
      {d_in[11], b2c,    4096},
      {d_in[12], wqc,    128 * 1024},
      {d_in[14], wconvc, 32 * 2 * 31},
      {d_in[15], wdensec, 128 * 32},
      {d_in[16], vvc,    128},
      {d_in[17], wprojc, 513 * 1536},
      {d_in[18], bprojc, 513},
  };
  for (int i = 0; i < 12; ++i) {
    int blocks = (jobs[i].n + 255) / 256;
    if (blocks > 512) blocks = 512;
    k_cvt<<<blocks, 256, 0, stream>>>(jobs[i].src, jobs[i].dst, jobs[i].n, flag);
  }

  k_init<<<32, 256, 0, stream>>>(h1g, h2g, ctxg, c1g, c2g, alignf, cumf, bar_cnt, bar_gen);
  k_prenet<<<DEC_T_, 256, 0, stream>>>(feats, go, w0, w1, pre, flag);
  k_mem<<<256, 256, 0, stream>>>(enc, d_in[13], mem_t, pm, flag);

  // allow >64KB dynamic LDS (ROCm generally permits up to device max; attribute call is belt&braces)
  (void)hipFuncSetAttribute((const void*)k_main,
                            hipFuncAttributeMaxDynamicSharedMemorySize, LDS_BYTES);
  k_main<<<NWG_, 256, LDS_BYTES, stream>>>(wih1, whh1, b1c, wih2, whh2, b2c, wqc, wconvc,
                                           wdensec, vvc, wprojc, bprojc, lens_d, pre, mem_t,
                                           pm, s_tmp, h1g, h2g, ctxg, c1g, c2g, alignf, cumf,
                                           bar_cnt, bar_gen, outf, outa);
}